// Round 1
// baseline (376.010 us; speedup 1.0000x reference)
//
#include <hip/hip_runtime.h>
#include <hip/hip_bf16.h>
#include <cmath>

// Problem constants (from reference)
#define NTOK 4096      // B*T
#define Dm   512
#define Hm   1024
#define Sm   2
#define Gm   2
#define NGm  6
#define Cm   32
#define Km   3
#define NEVm 50
#define NBANK 14       // 2 shared + 12 group banks
#define Em   4         // S+G

typedef __bf16 bf16x8 __attribute__((ext_vector_type(8)));
typedef float  floatx4 __attribute__((ext_vector_type(4)));

// ---------------------------------------------------------------- utilities

__global__ void k_zero_counts(int* counts) {
    if (threadIdx.x < 8) counts[threadIdx.x] = 0;
}

__global__ void k_bucket(const int* __restrict__ ids, const int* __restrict__ e2g,
                         int* __restrict__ gids, int* counts, int* __restrict__ lists) {
    int n = blockIdx.x * 256 + threadIdx.x;
    if (n >= NTOK) return;
    int id = ids[n];
    id = id < 0 ? 0 : (id > NEVm - 1 ? NEVm - 1 : id);
    int g = e2g[id];
    gids[n] = g;
    int pos = atomicAdd(&counts[g], 1);
    lists[g * NTOK + pos] = n;
}

// fp32 -> bf16 elementwise (n multiple of 8)
__global__ void k_cvt(const float* __restrict__ in, __bf16* __restrict__ out, int n) {
    int i = (blockIdx.x * 256 + threadIdx.x) * 8;
    if (i >= n) return;
    float4 a = *(const float4*)(in + i);
    float4 b = *(const float4*)(in + i + 4);
    bf16x8 v;
    v[0] = (__bf16)a.x; v[1] = (__bf16)a.y; v[2] = (__bf16)a.z; v[3] = (__bf16)a.w;
    v[4] = (__bf16)b.x; v[5] = (__bf16)b.y; v[6] = (__bf16)b.z; v[7] = (__bf16)b.w;
    *(bf16x8*)(out + i) = v;
}

// in: fp32 [nb][R][C] -> out: bf16 [nb][C][R]   (R,C multiples of 64)
// grid: (C/64, R/64, nb), block 256
__global__ __launch_bounds__(256) void k_transpose_cvt(const float* __restrict__ in,
                                                       __bf16* __restrict__ out,
                                                       int R, int C) {
    __shared__ float tile[64][65];
    const size_t bankoff = (size_t)blockIdx.z * R * C;
    const int r0 = blockIdx.y * 64, c0 = blockIdx.x * 64;
    const int t = threadIdx.x;
    {
        int r = t >> 2, cs = (t & 3) * 16;
        const float4* src = (const float4*)(in + bankoff + (size_t)(r0 + r) * C + c0 + cs);
        #pragma unroll
        for (int i = 0; i < 4; i++) {
            float4 v = src[i];
            tile[r][cs + i * 4 + 0] = v.x;
            tile[r][cs + i * 4 + 1] = v.y;
            tile[r][cs + i * 4 + 2] = v.z;
            tile[r][cs + i * 4 + 3] = v.w;
        }
    }
    __syncthreads();
    {
        int c = t >> 2, rs = (t & 3) * 16;
        __bf16* dst = out + bankoff + (size_t)(c0 + c) * R + r0 + rs;
        #pragma unroll
        for (int i = 0; i < 16; i++) dst[i] = (__bf16)tile[rs + i][c];
    }
}

// ---------------------------------------------------------------- FFN GEMM 1
// h[tok][e][j] = relu( x[tok][:] @ W1_bank + b1_bank )   (bf16 out)
// A: xb gathered rows [64 x 512], B: W1t[bank] = [H][D] (n-major, k contiguous)
// grid: (64 mtiles, 16 ntiles, 14 banks), block 256
__global__ __launch_bounds__(256) void k_ffn1(
    const __bf16* __restrict__ xb, const __bf16* __restrict__ W1t,
    const float* __restrict__ bs1, const float* __restrict__ bg1,
    const int* __restrict__ counts, const int* __restrict__ lists,
    __bf16* __restrict__ hb)
{
    const int bank = blockIdx.z;
    const int m0 = blockIdx.x * 64;
    const int n0 = blockIdx.y * 64;

    int cnt = NTOK;
    if (bank >= 2) {
        cnt = counts[(bank - 2) >> 1];
        if (m0 >= cnt) return;
    }

    __shared__ int tok_lds[64];
    __shared__ __align__(16) __bf16 A_lds[64 * 40];
    __shared__ __align__(16) __bf16 B_lds[64 * 40];

    const int t = threadIdx.x;
    if (t < 64) {
        int idx = m0 + t;
        int tok = -1;
        if (idx < cnt) tok = (bank < 2) ? idx : lists[((bank - 2) >> 1) * NTOK + idx];
        tok_lds[t] = tok;
    }
    __syncthreads();

    const int row = t >> 2, seg = t & 3;
    const int tok_a = tok_lds[row];
    const __bf16* aptr = (tok_a >= 0) ? (xb + (size_t)tok_a * Dm + seg * 8) : nullptr;
    const __bf16* bptr = W1t + (size_t)bank * Hm * Dm + (size_t)(n0 + row) * Dm + seg * 8;

    const int lane = t & 63, wave = t >> 6;
    const int col = lane & 15, quad = lane >> 4;

    floatx4 acc[4] = {};
    const bf16x8 zero8 = {};

    #pragma unroll 1
    for (int kt = 0; kt < Dm / 32; kt++) {
        bf16x8 av = zero8;
        if (aptr) av = *(const bf16x8*)(aptr + kt * 32);
        bf16x8 bv = *(const bf16x8*)(bptr + kt * 32);
        __syncthreads();
        *(bf16x8*)&A_lds[row * 40 + seg * 8] = av;
        *(bf16x8*)&B_lds[row * 40 + seg * 8] = bv;
        __syncthreads();
        bf16x8 bfr = *(const bf16x8*)&B_lds[(wave * 16 + col) * 40 + quad * 8];
        #pragma unroll
        for (int mt = 0; mt < 4; mt++) {
            bf16x8 afr = *(const bf16x8*)&A_lds[(mt * 16 + col) * 40 + quad * 8];
            acc[mt] = __builtin_amdgcn_mfma_f32_16x16x32_bf16(afr, bfr, acc[mt], 0, 0, 0);
        }
    }

    const int e = (bank < 2) ? bank : 2 + ((bank - 2) & 1);
    const float* b1p = (bank < 2) ? (bs1 + bank * Hm) : (bg1 + (size_t)(bank - 2) * Hm);
    const int n = n0 + wave * 16 + col;
    const float bias = b1p[n];

    #pragma unroll
    for (int mt = 0; mt < 4; mt++) {
        #pragma unroll
        for (int r = 0; r < 4; r++) {
            int m = mt * 16 + quad * 4 + r;
            int tok = tok_lds[m];
            if (tok >= 0) {
                float v = acc[mt][r] + bias;
                v = fmaxf(v, 0.0f);
                hb[((size_t)tok * Em + e) * Hm + n] = (__bf16)v;
            }
        }
    }
}

// ---------------------------------------------------------------- FFN GEMM 2
// eo[tok][e][d] = h[tok][e][:] @ W2_bank + b2_bank   (fp32 out)
// grid: (64 mtiles, 8 ntiles, 14 banks), block 256
__global__ __launch_bounds__(256) void k_ffn2(
    const __bf16* __restrict__ hb, const __bf16* __restrict__ W2t,
    const float* __restrict__ bs2, const float* __restrict__ bg2,
    const int* __restrict__ counts, const int* __restrict__ lists,
    float* __restrict__ eo)
{
    const int bank = blockIdx.z;
    const int m0 = blockIdx.x * 64;
    const int n0 = blockIdx.y * 64;

    int cnt = NTOK;
    if (bank >= 2) {
        cnt = counts[(bank - 2) >> 1];
        if (m0 >= cnt) return;
    }
    const int e = (bank < 2) ? bank : 2 + ((bank - 2) & 1);

    __shared__ int tok_lds[64];
    __shared__ __align__(16) __bf16 A_lds[64 * 40];
    __shared__ __align__(16) __bf16 B_lds[64 * 40];

    const int t = threadIdx.x;
    if (t < 64) {
        int idx = m0 + t;
        int tok = -1;
        if (idx < cnt) tok = (bank < 2) ? idx : lists[((bank - 2) >> 1) * NTOK + idx];
        tok_lds[t] = tok;
    }
    __syncthreads();

    const int row = t >> 2, seg = t & 3;
    const int tok_a = tok_lds[row];
    const __bf16* aptr = (tok_a >= 0) ? (hb + ((size_t)tok_a * Em + e) * Hm + seg * 8) : nullptr;
    const __bf16* bptr = W2t + (size_t)bank * Dm * Hm + (size_t)(n0 + row) * Hm + seg * 8;

    const int lane = t & 63, wave = t >> 6;
    const int col = lane & 15, quad = lane >> 4;

    floatx4 acc[4] = {};
    const bf16x8 zero8 = {};

    #pragma unroll 1
    for (int kt = 0; kt < Hm / 32; kt++) {
        bf16x8 av = zero8;
        if (aptr) av = *(const bf16x8*)(aptr + kt * 32);
        bf16x8 bv = *(const bf16x8*)(bptr + kt * 32);
        __syncthreads();
        *(bf16x8*)&A_lds[row * 40 + seg * 8] = av;
        *(bf16x8*)&B_lds[row * 40 + seg * 8] = bv;
        __syncthreads();
        bf16x8 bfr = *(const bf16x8*)&B_lds[(wave * 16 + col) * 40 + quad * 8];
        #pragma unroll
        for (int mt = 0; mt < 4; mt++) {
            bf16x8 afr = *(const bf16x8*)&A_lds[(mt * 16 + col) * 40 + quad * 8];
            acc[mt] = __builtin_amdgcn_mfma_f32_16x16x32_bf16(afr, bfr, acc[mt], 0, 0, 0);
        }
    }

    const float* b2p = (bank < 2) ? (bs2 + bank * Dm) : (bg2 + (size_t)(bank - 2) * Dm);
    const int n = n0 + wave * 16 + col;
    const float bias = b2p[n];

    #pragma unroll
    for (int mt = 0; mt < 4; mt++) {
        #pragma unroll
        for (int r = 0; r < 4; r++) {
            int m = mt * 16 + quad * 4 + r;
            int tok = tok_lds[m];
            if (tok >= 0) {
                eo[((size_t)tok * Em + e) * Dm + n] = acc[mt][r] + bias;
            }
        }
    }
}

// ---------------------------------------------------------------- gate
// logits[n][k][e] = [x,cond] @ gate_W[k] + gate_b[k]; softmax over e
// grid 64 blocks x 256 threads: 64 tokens/block, (token, e) per thread
__global__ __launch_bounds__(256) void k_gate(
    const float* __restrict__ x, const float* __restrict__ cond_emb,
    const int* __restrict__ gids, const float* __restrict__ gate_W,
    const float* __restrict__ gate_b, float* __restrict__ wts)
{
    __shared__ float lg[64][13];
    const int t = threadIdx.x;
    const int lt = t >> 2, e = t & 3;
    const int n = blockIdx.x * 64 + lt;
    const int gid = gids[n];

    float a0 = gate_b[0 * Em + e];
    float a1 = gate_b[1 * Em + e];
    float a2 = gate_b[2 * Em + e];
    const float* xr = x + (size_t)n * Dm;
    for (int f = 0; f < Dm; f++) {
        float xv = xr[f];
        a0 += xv * gate_W[(0 * 544 + f) * Em + e];
        a1 += xv * gate_W[(1 * 544 + f) * Em + e];
        a2 += xv * gate_W[(2 * 544 + f) * Em + e];
    }
    const float* ce = cond_emb + gid * Cm;
    for (int f = 0; f < Cm; f++) {
        float xv = ce[f];
        a0 += xv * gate_W[(0 * 544 + Dm + f) * Em + e];
        a1 += xv * gate_W[(1 * 544 + Dm + f) * Em + e];
        a2 += xv * gate_W[(2 * 544 + Dm + f) * Em + e];
    }
    lg[lt][0 + e] = a0;
    lg[lt][4 + e] = a1;
    lg[lt][8 + e] = a2;
    __syncthreads();

    if (t < 192) {
        int tk = t % 3, tn = t / 3;
        float* p = &lg[tn][tk * 4];
        float m = fmaxf(fmaxf(p[0], p[1]), fmaxf(p[2], p[3]));
        float e0 = expf(p[0] - m), e1 = expf(p[1] - m), e2 = expf(p[2] - m), e3 = expf(p[3] - m);
        float inv = 1.0f / (e0 + e1 + e2 + e3);
        int nn = blockIdx.x * 64 + tn;
        float* w = wts + (size_t)nn * (Km * Em) + tk * Em;
        w[0] = e0 * inv; w[1] = e1 * inv; w[2] = e2 * inv; w[3] = e3 * inv;
    }
}

// ---------------------------------------------------------------- combine
// out[k][n][d] = sum_e wts[n][k][e] * eo[n][e][d]
// grid 1024 blocks x 256: 4 tokens/block, 64 lanes x 8 d per token
__global__ __launch_bounds__(256) void k_combine(
    const float* __restrict__ eo, const float* __restrict__ wts,
    float* __restrict__ out)
{
    const int t = threadIdx.x;
    const int tok = blockIdx.x * 4 + (t >> 6);
    const int d0 = (t & 63) * 8;
    const float* ep = eo + (size_t)tok * Em * Dm;

    float w[Km][Em];
    #pragma unroll
    for (int k = 0; k < Km; k++)
        #pragma unroll
        for (int e = 0; e < Em; e++)
            w[k][e] = wts[(size_t)tok * (Km * Em) + k * Em + e];

    float4 o0[Km], o1[Km];
    #pragma unroll
    for (int k = 0; k < Km; k++) { o0[k] = make_float4(0, 0, 0, 0); o1[k] = make_float4(0, 0, 0, 0); }

    #pragma unroll
    for (int e = 0; e < Em; e++) {
        float4 a = *(const float4*)(ep + (size_t)e * Dm + d0);
        float4 b = *(const float4*)(ep + (size_t)e * Dm + d0 + 4);
        #pragma unroll
        for (int k = 0; k < Km; k++) {
            float wk = w[k][e];
            o0[k].x += wk * a.x; o0[k].y += wk * a.y; o0[k].z += wk * a.z; o0[k].w += wk * a.w;
            o1[k].x += wk * b.x; o1[k].y += wk * b.y; o1[k].z += wk * b.z; o1[k].w += wk * b.w;
        }
    }
    #pragma unroll
    for (int k = 0; k < Km; k++) {
        float* op = out + ((size_t)k * NTOK + tok) * Dm + d0;
        *(float4*)op = o0[k];
        *(float4*)(op + 4) = o1[k];
    }
}

// ---------------------------------------------------------------- launch

static inline size_t align256(size_t v) { return (v + 255) & ~(size_t)255; }

extern "C" void kernel_launch(void* const* d_in, const int* in_sizes, int n_in,
                              void* d_out, int out_size, void* d_ws, size_t ws_size,
                              hipStream_t stream) {
    const float* x        = (const float*)d_in[0];
    const int*   ids      = (const int*)d_in[1];
    const int*   e2g      = (const int*)d_in[2];
    const float* Ws1      = (const float*)d_in[3];
    const float* bs1      = (const float*)d_in[4];
    const float* Ws2      = (const float*)d_in[5];
    const float* bs2      = (const float*)d_in[6];
    const float* Wg1      = (const float*)d_in[7];
    const float* bg1      = (const float*)d_in[8];
    const float* Wg2      = (const float*)d_in[9];
    const float* bg2      = (const float*)d_in[10];
    const float* cond_emb = (const float*)d_in[11];
    const float* gate_W   = (const float*)d_in[12];
    const float* gate_b   = (const float*)d_in[13];
    float* out = (float*)d_out;

    // workspace carve (all 256B-aligned)
    char* ws = (char*)d_ws;
    size_t off = 0;
    const size_t HD = (size_t)Hm * Dm;         // 524288

    __bf16* xb  = (__bf16*)(ws + off); off = align256(off + (size_t)NTOK * Dm * 2);
    __bf16* W1t = (__bf16*)(ws + off); off = align256(off + (size_t)NBANK * HD * 2);
    __bf16* W2t = (__bf16*)(ws + off); off = align256(off + (size_t)NBANK * HD * 2);
    __bf16* hb  = (__bf16*)(ws + off); off = align256(off + (size_t)NTOK * Em * Hm * 2);
    float*  eo  = (float*)(ws + off);  off = align256(off + (size_t)NTOK * Em * Dm * 4);
    int*    gids   = (int*)(ws + off); off = align256(off + (size_t)NTOK * 4);
    int*    counts = (int*)(ws + off); off = align256(off + 256);
    int*    lists  = (int*)(ws + off); off = align256(off + (size_t)NGm * NTOK * 4);
    float*  wts    = (float*)(ws + off); off = align256(off + (size_t)NTOK * Km * Em * 4);
    (void)ws_size; (void)n_in; (void)in_sizes; (void)out_size;

    // 1) bucket tokens by group
    k_zero_counts<<<1, 64, 0, stream>>>(counts);
    k_bucket<<<NTOK / 256, 256, 0, stream>>>(ids, e2g, gids, counts, lists);

    // 2) conversions
    k_cvt<<<(NTOK * Dm) / (8 * 256), 256, 0, stream>>>(x, xb, NTOK * Dm);
    // W1t[bank][h][d] <- W1[bank][d][h]  (R=512, C=1024)
    k_transpose_cvt<<<dim3(Hm / 64, Dm / 64, 2), 256, 0, stream>>>(Ws1, W1t, Dm, Hm);
    k_transpose_cvt<<<dim3(Hm / 64, Dm / 64, 12), 256, 0, stream>>>(Wg1, W1t + 2 * HD, Dm, Hm);
    // W2t[bank][d][h] <- W2[bank][h][d]  (R=1024, C=512)
    k_transpose_cvt<<<dim3(Dm / 64, Hm / 64, 2), 256, 0, stream>>>(Ws2, W2t, Hm, Dm);
    k_transpose_cvt<<<dim3(Dm / 64, Hm / 64, 12), 256, 0, stream>>>(Wg2, W2t + 2 * HD, Hm, Dm);

    // 3) FFN layer 1 (relu epilogue, bf16 out)
    k_ffn1<<<dim3(NTOK / 64, Hm / 64, NBANK), 256, 0, stream>>>(
        xb, W1t, bs1, bg1, counts, lists, hb);

    // 4) FFN layer 2 (fp32 out)
    k_ffn2<<<dim3(NTOK / 64, Dm / 64, NBANK), 256, 0, stream>>>(
        hb, W2t, bs2, bg2, counts, lists, eo);

    // 5) gates
    k_gate<<<NTOK / 64, 256, 0, stream>>>(x, cond_emb, gids, gate_W, gate_b, wts);

    // 6) combine
    k_combine<<<NTOK / 4, 256, 0, stream>>>(eo, wts, out);
}

// Round 2
// 356.008 us; speedup vs baseline: 1.0562x; 1.0562x over previous
//
#include <hip/hip_runtime.h>
#include <hip/hip_bf16.h>
#include <cmath>

// Problem constants (from reference)
#define NTOK 4096      // B*T
#define Dm   512
#define Hm   1024
#define Cm   32
#define Km   3
#define NEVm 50
#define NGm  6
#define NBANK 14       // 2 shared + 12 group banks
#define Em   4         // S+G

typedef __bf16 bf16x8 __attribute__((ext_vector_type(8)));
typedef float  floatx4 __attribute__((ext_vector_type(4)));

// async global->LDS 16B: per-lane global addr, wave-uniform LDS base + lane*16
__device__ __forceinline__ void async16(const void* g, void* l) {
    __builtin_amdgcn_global_load_lds(
        (const __attribute__((address_space(1))) void*)g,
        (__attribute__((address_space(3))) void*)l, 16, 0, 0);
}

// ---------------------------------------------------------------- utilities

__global__ void k_zero_counts(int* counts) {
    if (threadIdx.x < 8) counts[threadIdx.x] = 0;
}

__global__ void k_bucket(const int* __restrict__ ids, const int* __restrict__ e2g,
                         int* __restrict__ gids, int* counts, int* __restrict__ lists) {
    int n = blockIdx.x * 256 + threadIdx.x;
    if (n >= NTOK) return;
    int id = ids[n];
    id = id < 0 ? 0 : (id > NEVm - 1 ? NEVm - 1 : id);
    int g = e2g[id];
    gids[n] = g;
    int pos = atomicAdd(&counts[g], 1);
    lists[g * NTOK + pos] = n;
}

// fp32 -> bf16 elementwise (n multiple of 2048)
__global__ void k_cvt(const float* __restrict__ in, __bf16* __restrict__ out, int n) {
    int i = (blockIdx.x * 256 + threadIdx.x) * 8;
    if (i >= n) return;
    float4 a = *(const float4*)(in + i);
    float4 b = *(const float4*)(in + i + 4);
    bf16x8 v;
    v[0] = (__bf16)a.x; v[1] = (__bf16)a.y; v[2] = (__bf16)a.z; v[3] = (__bf16)a.w;
    v[4] = (__bf16)b.x; v[5] = (__bf16)b.y; v[6] = (__bf16)b.z; v[7] = (__bf16)b.w;
    *(bf16x8*)(out + i) = v;
}

// in: fp32 [nb][R][C] -> out: bf16 [nb][C][R]   (R,C multiples of 64)
// grid: (C/64, R/64, nb), block 256
__global__ __launch_bounds__(256) void k_transpose_cvt(const float* __restrict__ in,
                                                       __bf16* __restrict__ out,
                                                       int R, int C) {
    __shared__ float tile[64][65];
    const size_t bankoff = (size_t)blockIdx.z * R * C;
    const int r0 = blockIdx.y * 64, c0 = blockIdx.x * 64;
    const int t = threadIdx.x;
    {
        int r = t >> 2, cs = (t & 3) * 16;
        const float4* src = (const float4*)(in + bankoff + (size_t)(r0 + r) * C + c0 + cs);
        #pragma unroll
        for (int i = 0; i < 4; i++) {
            float4 v = src[i];
            tile[r][cs + i * 4 + 0] = v.x;
            tile[r][cs + i * 4 + 1] = v.y;
            tile[r][cs + i * 4 + 2] = v.z;
            tile[r][cs + i * 4 + 3] = v.w;
        }
    }
    __syncthreads();
    {
        int c = t >> 2, rs = (t & 3) * 16;
        __bf16* dst = out + bankoff + (size_t)(c0 + c) * R + r0 + rs;
        bf16x8 v0, v1;
        #pragma unroll
        for (int i = 0; i < 8; i++) v0[i] = (__bf16)tile[rs + i][c];
        #pragma unroll
        for (int i = 0; i < 8; i++) v1[i] = (__bf16)tile[rs + 8 + i][c];
        *(bf16x8*)dst = v0;
        *(bf16x8*)(dst + 8) = v1;
    }
}

// ---------------------------------------------------------------- FFN GEMM 1
// h[tok][e][j] = relu( x[tok][:] @ W1_bank + b1_bank )   (bf16 out)
// 128x128 tile, BK=32, 4 waves 2x2, global_load_lds staging (m97 structure)
// grid: (32, 8, 14), block 256
__global__ __launch_bounds__(256) void k_ffn1(
    const __bf16* __restrict__ xb, const __bf16* __restrict__ W1t,
    const float* __restrict__ bs1, const float* __restrict__ bg1,
    const int* __restrict__ counts, const int* __restrict__ lists,
    __bf16* __restrict__ hb)
{
    const int bank = blockIdx.z;
    const int m0 = blockIdx.x * 128;
    const int n0 = blockIdx.y * 128;

    int cnt = NTOK;
    if (bank >= 2) {
        cnt = counts[(bank - 2) >> 1];
        if (m0 >= cnt) return;
    }

    __shared__ int tok_lds[128];
    __shared__ __align__(16) __bf16 A_lds[128 * 32];
    __shared__ __align__(16) __bf16 B_lds[128 * 32];

    const int t = threadIdx.x;
    if (t < 128) {
        int idx = m0 + t;
        int tok = -1;
        if (idx < cnt) tok = (bank < 2) ? idx : lists[((bank - 2) >> 1) * NTOK + idx];
        tok_lds[t] = tok;
    }
    __syncthreads();

    // staging addressing: thread t covers rows (t>>2) and (t>>2)+64, kseg (t&3)*8
    const int srow = t >> 2;
    const int skseg = (t & 3) * 8;
    const int wave = t >> 6, lane = t & 63;
    int tokA0 = tok_lds[srow];      if (tokA0 < 0) tokA0 = 0;
    int tokA1 = tok_lds[srow + 64]; if (tokA1 < 0) tokA1 = 0;
    const __bf16* ga0 = xb + (size_t)tokA0 * Dm + skseg;
    const __bf16* ga1 = xb + (size_t)tokA1 * Dm + skseg;
    const __bf16* gb0 = W1t + (size_t)bank * Hm * Dm + (size_t)(n0 + srow) * Dm + skseg;
    const __bf16* gb1 = gb0 + (size_t)64 * Dm;
    char* ldsA = (char*)A_lds + wave * 1024;
    char* ldsB = (char*)B_lds + wave * 1024;

    // fragment addressing (constant across K-loop)
    const int col = lane & 15, quad = lane >> 4;
    const int mh = (wave >> 1) * 64, nh = (wave & 1) * 64;
    const __bf16* afp[4]; const __bf16* bfp[4];
    #pragma unroll
    for (int i = 0; i < 4; i++) {
        afp[i] = &A_lds[(mh + i * 16 + col) * 32 + quad * 8];
        bfp[i] = &B_lds[(nh + i * 16 + col) * 32 + quad * 8];
    }

    floatx4 acc[4][4] = {};

    #pragma unroll 1
    for (int kt = 0; kt < Dm / 32; kt++) {
        const int ko = kt * 32;
        async16(ga0 + ko, ldsA);
        async16(ga1 + ko, ldsA + 4096);
        async16(gb0 + ko, ldsB);
        async16(gb1 + ko, ldsB + 4096);
        __syncthreads();
        bf16x8 af[4], bfv[4];
        #pragma unroll
        for (int i = 0; i < 4; i++) af[i] = *(const bf16x8*)afp[i];
        #pragma unroll
        for (int i = 0; i < 4; i++) bfv[i] = *(const bf16x8*)bfp[i];
        #pragma unroll
        for (int mt = 0; mt < 4; mt++)
            #pragma unroll
            for (int nt = 0; nt < 4; nt++)
                acc[mt][nt] = __builtin_amdgcn_mfma_f32_16x16x32_bf16(af[mt], bfv[nt], acc[mt][nt], 0, 0, 0);
        __syncthreads();
    }

    const int e = (bank < 2) ? bank : 2 + ((bank - 2) & 1);
    const float* b1p = (bank < 2) ? (bs1 + bank * Hm) : (bg1 + (size_t)(bank - 2) * Hm);
    float bias[4];
    #pragma unroll
    for (int nt = 0; nt < 4; nt++) bias[nt] = b1p[n0 + nh + nt * 16 + col];

    #pragma unroll
    for (int mt = 0; mt < 4; mt++) {
        #pragma unroll
        for (int r = 0; r < 4; r++) {
            int m = mh + mt * 16 + quad * 4 + r;
            int tok = tok_lds[m];
            if (tok >= 0) {
                __bf16* hrow = hb + ((size_t)tok * Em + e) * Hm + n0 + nh + col;
                #pragma unroll
                for (int nt = 0; nt < 4; nt++) {
                    float v = acc[mt][nt][r] + bias[nt];
                    hrow[nt * 16] = (__bf16)fmaxf(v, 0.0f);
                }
            }
        }
    }
}

// ---------------------------------------------------------------- FFN GEMM 2
// eo[tok][e][d] = h[tok][e][:] @ W2_bank + b2_bank   (fp32 out)
// grid: (32, 4, 14), block 256
__global__ __launch_bounds__(256) void k_ffn2(
    const __bf16* __restrict__ hb, const __bf16* __restrict__ W2t,
    const float* __restrict__ bs2, const float* __restrict__ bg2,
    const int* __restrict__ counts, const int* __restrict__ lists,
    float* __restrict__ eo)
{
    const int bank = blockIdx.z;
    const int m0 = blockIdx.x * 128;
    const int n0 = blockIdx.y * 128;

    int cnt = NTOK;
    if (bank >= 2) {
        cnt = counts[(bank - 2) >> 1];
        if (m0 >= cnt) return;
    }
    const int e = (bank < 2) ? bank : 2 + ((bank - 2) & 1);

    __shared__ int tok_lds[128];
    __shared__ __align__(16) __bf16 A_lds[128 * 32];
    __shared__ __align__(16) __bf16 B_lds[128 * 32];

    const int t = threadIdx.x;
    if (t < 128) {
        int idx = m0 + t;
        int tok = -1;
        if (idx < cnt) tok = (bank < 2) ? idx : lists[((bank - 2) >> 1) * NTOK + idx];
        tok_lds[t] = tok;
    }
    __syncthreads();

    const int srow = t >> 2;
    const int skseg = (t & 3) * 8;
    const int wave = t >> 6, lane = t & 63;
    int tokA0 = tok_lds[srow];      if (tokA0 < 0) tokA0 = 0;
    int tokA1 = tok_lds[srow + 64]; if (tokA1 < 0) tokA1 = 0;
    const __bf16* ga0 = hb + ((size_t)tokA0 * Em + e) * Hm + skseg;
    const __bf16* ga1 = hb + ((size_t)tokA1 * Em + e) * Hm + skseg;
    const __bf16* gb0 = W2t + (size_t)bank * Dm * Hm + (size_t)(n0 + srow) * Hm + skseg;
    const __bf16* gb1 = gb0 + (size_t)64 * Hm;
    char* ldsA = (char*)A_lds + wave * 1024;
    char* ldsB = (char*)B_lds + wave * 1024;

    const int col = lane & 15, quad = lane >> 4;
    const int mh = (wave >> 1) * 64, nh = (wave & 1) * 64;
    const __bf16* afp[4]; const __bf16* bfp[4];
    #pragma unroll
    for (int i = 0; i < 4; i++) {
        afp[i] = &A_lds[(mh + i * 16 + col) * 32 + quad * 8];
        bfp[i] = &B_lds[(nh + i * 16 + col) * 32 + quad * 8];
    }

    floatx4 acc[4][4] = {};

    #pragma unroll 1
    for (int kt = 0; kt < Hm / 32; kt++) {
        const int ko = kt * 32;
        async16(ga0 + ko, ldsA);
        async16(ga1 + ko, ldsA + 4096);
        async16(gb0 + ko, ldsB);
        async16(gb1 + ko, ldsB + 4096);
        __syncthreads();
        bf16x8 af[4], bfv[4];
        #pragma unroll
        for (int i = 0; i < 4; i++) af[i] = *(const bf16x8*)afp[i];
        #pragma unroll
        for (int i = 0; i < 4; i++) bfv[i] = *(const bf16x8*)bfp[i];
        #pragma unroll
        for (int mt = 0; mt < 4; mt++)
            #pragma unroll
            for (int nt = 0; nt < 4; nt++)
                acc[mt][nt] = __builtin_amdgcn_mfma_f32_16x16x32_bf16(af[mt], bfv[nt], acc[mt][nt], 0, 0, 0);
        __syncthreads();
    }

    const float* b2p = (bank < 2) ? (bs2 + bank * Dm) : (bg2 + (size_t)(bank - 2) * Dm);
    float bias[4];
    #pragma unroll
    for (int nt = 0; nt < 4; nt++) bias[nt] = b2p[n0 + nh + nt * 16 + col];

    #pragma unroll
    for (int mt = 0; mt < 4; mt++) {
        #pragma unroll
        for (int r = 0; r < 4; r++) {
            int m = mh + mt * 16 + quad * 4 + r;
            int tok = tok_lds[m];
            if (tok >= 0) {
                float* erow = eo + ((size_t)tok * Em + e) * Dm + n0 + nh + col;
                #pragma unroll
                for (int nt = 0; nt < 4; nt++)
                    erow[nt * 16] = acc[mt][nt][r] + bias[nt];
            }
        }
    }
}

// ---------------------------------------------------------------- gate
// wave-per-token: lane-strided features, coalesced float4 gate_W reads,
// butterfly reduce, lanes 0..2 do per-task softmax.
// grid 1024 blocks x 256 threads (4 tokens/block)
__global__ __launch_bounds__(256) void k_gate(
    const float* __restrict__ x, const float* __restrict__ cond_emb,
    const int* __restrict__ gids, const float* __restrict__ gW,
    const float* __restrict__ gb, float* __restrict__ wts)
{
    const int t = threadIdx.x;
    const int wave = t >> 6, lane = t & 63;
    const int n = blockIdx.x * 4 + wave;
    const int gid = gids[n];
    const float* xr = x + (size_t)n * Dm;
    const float* ce = cond_emb + gid * Cm;

    float a[Km][Em] = {};
    for (int f = lane; f < Dm + Cm; f += 64) {
        float xv = (f < Dm) ? xr[f] : ce[f - Dm];
        #pragma unroll
        for (int k = 0; k < Km; k++) {
            float4 w = *(const float4*)(gW + ((size_t)k * (Dm + Cm) + f) * Em);
            a[k][0] += xv * w.x; a[k][1] += xv * w.y;
            a[k][2] += xv * w.z; a[k][3] += xv * w.w;
        }
    }
    #pragma unroll
    for (int off = 1; off < 64; off <<= 1)
        #pragma unroll
        for (int k = 0; k < Km; k++)
            #pragma unroll
            for (int e = 0; e < Em; e++)
                a[k][e] += __shfl_xor(a[k][e], off, 64);

    if (lane < Km) {
        int k = lane;
        float v0 = a[k][0] + gb[k * Em + 0];
        float v1 = a[k][1] + gb[k * Em + 1];
        float v2 = a[k][2] + gb[k * Em + 2];
        float v3 = a[k][3] + gb[k * Em + 3];
        float m = fmaxf(fmaxf(v0, v1), fmaxf(v2, v3));
        float e0 = __expf(v0 - m), e1 = __expf(v1 - m), e2 = __expf(v2 - m), e3 = __expf(v3 - m);
        float inv = 1.0f / (e0 + e1 + e2 + e3);
        float4 w = make_float4(e0 * inv, e1 * inv, e2 * inv, e3 * inv);
        *(float4*)(wts + (size_t)n * (Km * Em) + k * Em) = w;
    }
}

// ---------------------------------------------------------------- combine
// out[k][n][d] = sum_e wts[n][k][e] * eo[n][e][d]
__global__ __launch_bounds__(256) void k_combine(
    const float* __restrict__ eo, const float* __restrict__ wts,
    float* __restrict__ out)
{
    const int t = threadIdx.x;
    const int tok = blockIdx.x * 4 + (t >> 6);
    const int d0 = (t & 63) * 8;
    const float* ep = eo + (size_t)tok * Em * Dm;

    float w[Km][Em];
    #pragma unroll
    for (int k = 0; k < Km; k++)
        #pragma unroll
        for (int e = 0; e < Em; e++)
            w[k][e] = wts[(size_t)tok * (Km * Em) + k * Em + e];

    float4 o0[Km], o1[Km];
    #pragma unroll
    for (int k = 0; k < Km; k++) { o0[k] = make_float4(0, 0, 0, 0); o1[k] = make_float4(0, 0, 0, 0); }

    #pragma unroll
    for (int e = 0; e < Em; e++) {
        float4 a = *(const float4*)(ep + (size_t)e * Dm + d0);
        float4 b = *(const float4*)(ep + (size_t)e * Dm + d0 + 4);
        #pragma unroll
        for (int k = 0; k < Km; k++) {
            float wk = w[k][e];
            o0[k].x += wk * a.x; o0[k].y += wk * a.y; o0[k].z += wk * a.z; o0[k].w += wk * a.w;
            o1[k].x += wk * b.x; o1[k].y += wk * b.y; o1[k].z += wk * b.z; o1[k].w += wk * b.w;
        }
    }
    #pragma unroll
    for (int k = 0; k < Km; k++) {
        float* op = out + ((size_t)k * NTOK + tok) * Dm + d0;
        *(float4*)op = o0[k];
        *(float4*)(op + 4) = o1[k];
    }
}

// ---------------------------------------------------------------- launch

static inline size_t align256(size_t v) { return (v + 255) & ~(size_t)255; }

extern "C" void kernel_launch(void* const* d_in, const int* in_sizes, int n_in,
                              void* d_out, int out_size, void* d_ws, size_t ws_size,
                              hipStream_t stream) {
    const float* x        = (const float*)d_in[0];
    const int*   ids      = (const int*)d_in[1];
    const int*   e2g      = (const int*)d_in[2];
    const float* Ws1      = (const float*)d_in[3];
    const float* bs1      = (const float*)d_in[4];
    const float* Ws2      = (const float*)d_in[5];
    const float* bs2      = (const float*)d_in[6];
    const float* Wg1      = (const float*)d_in[7];
    const float* bg1      = (const float*)d_in[8];
    const float* Wg2      = (const float*)d_in[9];
    const float* bg2      = (const float*)d_in[10];
    const float* cond_emb = (const float*)d_in[11];
    const float* gate_W   = (const float*)d_in[12];
    const float* gate_b   = (const float*)d_in[13];
    float* out = (float*)d_out;

    char* ws = (char*)d_ws;
    size_t off = 0;
    const size_t HD = (size_t)Hm * Dm;

    __bf16* xb  = (__bf16*)(ws + off); off = align256(off + (size_t)NTOK * Dm * 2);
    __bf16* W1t = (__bf16*)(ws + off); off = align256(off + (size_t)NBANK * HD * 2);
    __bf16* W2t = (__bf16*)(ws + off); off = align256(off + (size_t)NBANK * HD * 2);
    __bf16* hb  = (__bf16*)(ws + off); off = align256(off + (size_t)NTOK * Em * Hm * 2);
    float*  eo  = (float*)(ws + off);  off = align256(off + (size_t)NTOK * Em * Dm * 4);
    int*    gids   = (int*)(ws + off); off = align256(off + (size_t)NTOK * 4);
    int*    counts = (int*)(ws + off); off = align256(off + 256);
    int*    lists  = (int*)(ws + off); off = align256(off + (size_t)NGm * NTOK * 4);
    float*  wts    = (float*)(ws + off); off = align256(off + (size_t)NTOK * Km * Em * 4);
    (void)ws_size; (void)n_in; (void)in_sizes; (void)out_size;

    // 1) bucket tokens by group
    k_zero_counts<<<1, 64, 0, stream>>>(counts);
    k_bucket<<<NTOK / 256, 256, 0, stream>>>(ids, e2g, gids, counts, lists);

    // 2) conversions
    k_cvt<<<(NTOK * Dm) / (8 * 256), 256, 0, stream>>>(x, xb, NTOK * Dm);
    k_transpose_cvt<<<dim3(Hm / 64, Dm / 64, 2), 256, 0, stream>>>(Ws1, W1t, Dm, Hm);
    k_transpose_cvt<<<dim3(Hm / 64, Dm / 64, 12), 256, 0, stream>>>(Wg1, W1t + 2 * HD, Dm, Hm);
    k_transpose_cvt<<<dim3(Dm / 64, Hm / 64, 2), 256, 0, stream>>>(Ws2, W2t, Hm, Dm);
    k_transpose_cvt<<<dim3(Dm / 64, Hm / 64, 12), 256, 0, stream>>>(Wg2, W2t + 2 * HD, Hm, Dm);

    // 3) FFN layer 1 (relu epilogue, bf16 out)
    k_ffn1<<<dim3(NTOK / 128, Hm / 128, NBANK), 256, 0, stream>>>(
        xb, W1t, bs1, bg1, counts, lists, hb);

    // 4) FFN layer 2 (fp32 out)
    k_ffn2<<<dim3(NTOK / 128, Dm / 128, NBANK), 256, 0, stream>>>(
        hb, W2t, bs2, bg2, counts, lists, eo);

    // 5) gates
    k_gate<<<NTOK / 4, 256, 0, stream>>>(x, cond_emb, gids, gate_W, gate_b, wts);

    // 6) combine
    k_combine<<<NTOK / 4, 256, 0, stream>>>(eo, wts, out);
}